// Round 2
// baseline (9128.218 us; speedup 1.0000x reference)
//
#include <hip/hip_runtime.h>
#include <math.h>

// Problem constants
#define NB 64      // batch
#define NS 128     // seq len
#define ND 1024    // input dim
#define NH 512     // hidden
#define NG 2048    // 4*H
#define NTOT 255   // 2S-1
#define NSTEPS 127 // S-1
#define NWV 511
#define NPV 152

// ws layout (floats):
//  xp   : [2][128][2048][64]  = 33,554,432
//  h_all: [2][128][512][64]   =  8,388,608
//  vec  : [64][255][512]      =  8,355,840
//  bar  : 128 ints
static const size_t XP_SZ  = (size_t)2 * NS * NG * NB;
static const size_t H_SZ   = (size_t)2 * NS * NH * NB;
static const size_t VEC_SZ = (size_t)NB * NTOT * NH;

__device__ __forceinline__ float sigm(float x) { return 1.f / (1.f + __expf(-x)); }

#define FMA4x4(acc, av, bv)                                                    \
  acc[0][0] += av.x * bv.x; acc[0][1] += av.x * bv.y;                          \
  acc[0][2] += av.x * bv.z; acc[0][3] += av.x * bv.w;                          \
  acc[1][0] += av.y * bv.x; acc[1][1] += av.y * bv.y;                          \
  acc[1][2] += av.y * bv.z; acc[1][3] += av.y * bv.w;                          \
  acc[2][0] += av.z * bv.x; acc[2][1] += av.z * bv.y;                          \
  acc[2][2] += av.z * bv.z; acc[2][3] += av.z * bv.w;                          \
  acc[3][0] += av.w * bv.x; acc[3][1] += av.w * bv.y;                          \
  acc[3][2] += av.w * bv.z; acc[3][3] += av.w * bv.w;

// ---------------- K1: xp[dir][t][grow][b] = elmo @ w_ih^T + bias ----------
// M = 8192 (m = t*64 + b), N = 4096 (dir*2048 + grow), K = 1024
__global__ __launch_bounds__(256) void k_xp(
    const float* __restrict__ elmo, const float* __restrict__ wf,
    const float* __restrict__ wb, const float* __restrict__ biasf,
    const float* __restrict__ biasb, float* __restrict__ xp,
    int* __restrict__ bar) {
  __shared__ float As[16][68];
  __shared__ float Bs[16][68];
  const int tid = threadIdx.x;
  if (blockIdx.x == 0 && blockIdx.y == 0 && tid < 128) bar[tid] = 0;  // for k_lstm
  const int n0 = blockIdx.x * 64;
  const int t  = blockIdx.y;          // tile rows are b = 0..63 at this t
  const int lr = tid >> 2, lc4 = (tid & 3) << 2;
  const int tx = tid & 15, ty = tid >> 4;
  float acc[4][4] = {};
  const float* arow = elmo + ((size_t)lr * NS + t) * ND;  // b = lr
  const int n = n0 + lr;
  const float* brow = (n < NG) ? (wf + (size_t)n * ND) : (wb + (size_t)(n - NG) * ND);
  for (int k0 = 0; k0 < ND; k0 += 16) {
    const float4 a4 = *(const float4*)(arow + k0 + lc4);
    As[lc4 + 0][lr] = a4.x; As[lc4 + 1][lr] = a4.y;
    As[lc4 + 2][lr] = a4.z; As[lc4 + 3][lr] = a4.w;
    const float4 b4 = *(const float4*)(brow + k0 + lc4);
    Bs[lc4 + 0][lr] = b4.x; Bs[lc4 + 1][lr] = b4.y;
    Bs[lc4 + 2][lr] = b4.z; Bs[lc4 + 3][lr] = b4.w;
    __syncthreads();
#pragma unroll
    for (int kk = 0; kk < 16; ++kk) {
      const float4 av = *(const float4*)&As[kk][ty << 2];
      const float4 bv = *(const float4*)&Bs[kk][tx << 2];
      FMA4x4(acc, av, bv)
    }
    __syncthreads();
  }
#pragma unroll
  for (int i = 0; i < 4; ++i) {
    const int b = (ty << 2) + i;
#pragma unroll
    for (int j = 0; j < 4; ++j) {
      const int nn = n0 + (tx << 2) + j;
      const int dir = nn >> 11, grow = nn & 2047;
      const float bias = dir ? biasb[grow] : biasf[grow];
      xp[(((size_t)dir * NS + t) * NG + grow) * NB + b] = acc[i][j] + bias;
    }
  }
}

// ---------------- K2: persistent BiLSTM scan with device barrier ----------
// 256 blocks x 256 thr. Block = (dir, 4 h-cols). Thread = (b, q). c in regs.
__global__ __launch_bounds__(256) void k_lstm(
    const float* __restrict__ whh_f, const float* __restrict__ whh_b,
    const float* __restrict__ xp, float* __restrict__ h_all,
    int* __restrict__ bar) {
  __shared__ float Wt[512][16];  // [k][q*4 + g]
  const int bid = blockIdx.x;
  const int dir = bid >> 7;
  const int col0 = (bid & 127) << 2;
  const int tid = threadIdx.x;
  const int b = tid & 63, q = tid >> 6;
  const int col = col0 + q;
  const float* whh = dir ? whh_b : whh_f;
  for (int idx = tid; idx < 8192; idx += 256) {
    const int k = idx >> 4, qq = (idx >> 2) & 3, g = idx & 3;
    Wt[k][(qq << 2) + g] = whh[(size_t)(g * NH + col0 + qq) * NH + k];
  }
  __syncthreads();
  const float* xpd = xp + (size_t)dir * NS * NG * NB;
  float* hd = h_all + (size_t)dir * NS * NH * NB;
  float c = 0.f;
  for (int t = 0; t < NS; ++t) {
    const int pos = dir ? (NS - 1 - t) : t;  // xp read + h store position
    const size_t xbase = (size_t)pos * NG * NB + b;
    float a0 = xpd[xbase + (size_t)(0 * NH + col) * NB];
    float a1 = xpd[xbase + (size_t)(1 * NH + col) * NB];
    float a2 = xpd[xbase + (size_t)(2 * NH + col) * NB];
    float a3 = xpd[xbase + (size_t)(3 * NH + col) * NB];
    if (t > 0) {
      const int prevpos = dir ? (NS - t) : (t - 1);
      const float* hp = hd + (size_t)prevpos * NH * NB + b;
#pragma unroll 8
      for (int k = 0; k < NH; ++k) {
        const float hk = hp[(size_t)k * NB];
        const float4 wv = *(const float4*)&Wt[k][q << 2];
        a0 += hk * wv.x; a1 += hk * wv.y; a2 += hk * wv.z; a3 += hk * wv.w;
      }
    }
    const float ig = sigm(a0), fg = sigm(a1), og = sigm(a3);
    const float gg = tanhf(a2);
    c = fg * c + ig * gg;
    const float h = og * tanhf(c);
    hd[((size_t)pos * NH + col) * NB + b] = h;
    if (t < NS - 1) {
      __threadfence();           // publish my h stores (agent scope)
      __syncthreads();
      if (tid == 0) {
        atomicAdd(&bar[t], 1);
        while (__hip_atomic_load(&bar[t], __ATOMIC_ACQUIRE,
                                 __HIP_MEMORY_SCOPE_AGENT) < 256) {
          __builtin_amdgcn_s_sleep(8);
        }
      }
      __syncthreads();
      __threadfence();           // acquire side: don't read stale h
    }
  }
}

// ---------------- K3: combined = lrelu(fwd@W1^T + bwd@W2^T) -> vec --------
__global__ __launch_bounds__(256) void k_comb(
    const float* __restrict__ h_all, const float* __restrict__ W1,
    const float* __restrict__ W2, float* __restrict__ vec) {
  __shared__ float A1[16][68], A2[16][68], B1[16][68], B2[16][68];
  const int tid = threadIdx.x;
  const int n0 = blockIdx.x * 64;
  const int s = blockIdx.y;
  const float* h0 = h_all + (size_t)s * NH * NB;
  const float* h1 = h_all + ((size_t)NS + s) * NH * NB;
  const int aj = tid >> 4, ai4 = (tid & 15) << 2;
  const int lr = tid >> 2, lc4 = (tid & 3) << 2;
  const int tx = tid & 15, ty = tid >> 4;
  const float* b1row = W1 + (size_t)(n0 + lr) * NH;
  const float* b2row = W2 + (size_t)(n0 + lr) * NH;
  float acc[4][4] = {};
  for (int k0 = 0; k0 < NH; k0 += 16) {
    *(float4*)&A1[aj][ai4] = *(const float4*)(h0 + (size_t)(k0 + aj) * NB + ai4);
    *(float4*)&A2[aj][ai4] = *(const float4*)(h1 + (size_t)(k0 + aj) * NB + ai4);
    const float4 w1 = *(const float4*)(b1row + k0 + lc4);
    B1[lc4 + 0][lr] = w1.x; B1[lc4 + 1][lr] = w1.y;
    B1[lc4 + 2][lr] = w1.z; B1[lc4 + 3][lr] = w1.w;
    const float4 w2 = *(const float4*)(b2row + k0 + lc4);
    B2[lc4 + 0][lr] = w2.x; B2[lc4 + 1][lr] = w2.y;
    B2[lc4 + 2][lr] = w2.z; B2[lc4 + 3][lr] = w2.w;
    __syncthreads();
#pragma unroll
    for (int kk = 0; kk < 16; ++kk) {
      const float4 a1 = *(const float4*)&A1[kk][ty << 2];
      const float4 b1 = *(const float4*)&B1[kk][tx << 2];
      FMA4x4(acc, a1, b1)
      const float4 a2 = *(const float4*)&A2[kk][ty << 2];
      const float4 b2 = *(const float4*)&B2[kk][tx << 2];
      FMA4x4(acc, a2, b2)
    }
    __syncthreads();
  }
#pragma unroll
  for (int i = 0; i < 4; ++i) {
    const int b = (ty << 2) + i;
#pragma unroll
    for (int j = 0; j < 4; ++j) {
      const int nn = n0 + (tx << 2) + j;
      float v = acc[i][j];
      v = v > 0.f ? v : 0.01f * v;
      vec[((size_t)b * NTOT + s) * NH + nn] = v;
    }
  }
}

// ---------------- K4: l2-normalize word rows of vec -----------------------
__global__ __launch_bounds__(256) void k_norm(float* __restrict__ vec) {
  const int row = (blockIdx.x << 2) + (threadIdx.x >> 6);  // 0..8191
  const int lane = threadIdx.x & 63;
  const int b = row >> 7, s = row & 127;
  float* p = vec + ((size_t)b * NTOT + s) * NH;
  float4 v0 = *(float4*)(p + (lane << 3));
  float4 v1 = *(float4*)(p + (lane << 3) + 4);
  float ss = v0.x * v0.x + v0.y * v0.y + v0.z * v0.z + v0.w * v0.w +
             v1.x * v1.x + v1.y * v1.y + v1.z * v1.z + v1.w * v1.w;
#pragma unroll
  for (int off = 32; off; off >>= 1) ss += __shfl_down(ss, off);
  ss = __shfl(ss, 0);
  const float sc = 1.f / fmaxf(sqrtf(ss), 1e-12f);
  v0.x *= sc; v0.y *= sc; v0.z *= sc; v0.w *= sc;
  v1.x *= sc; v1.y *= sc; v1.z *= sc; v1.w *= sc;
  *(float4*)(p + (lane << 3)) = v0;
  *(float4*)(p + (lane << 3) + 4) = v1;
}

// ---------------- K5: per-batch tree composition scan ---------------------
// c[k] = sum_j lv[j]*rv[(j+k)&511], then l2n.  (input l2n folds into output.)
__global__ __launch_bounds__(512) void k_compose(
    float* __restrict__ vec, const int* __restrict__ cinfo) {
  __shared__ float lv[512];
  __shared__ float rvd[1028];
  __shared__ float cpart[4][512];
  __shared__ float red[9];
  const int b = blockIdx.x;
  const int tid = threadIdx.x;
  float* vb = vec + (size_t)b * NTOT * NH;
  const int* ib = cinfo + b * NSTEPS * 4;
  const int jq = tid >> 7;
  const int k4 = (tid & 127) << 2;
  const int wid = tid >> 6, lane = tid & 63;
  for (int i = 0; i < NSTEPS; ++i) {
    const int tt = ib[i * 4 + 0], p = ib[i * 4 + 1];
    const int l = ib[i * 4 + 2], r = ib[i * 4 + 3];
    lv[tid] = vb[(size_t)l * NH + tid];
    const float rvv = vb[(size_t)r * NH + tid];
    rvd[tid] = rvv;
    rvd[512 + tid] = rvv;
    __syncthreads();
    float a0 = 0.f, a1 = 0.f, a2 = 0.f, a3 = 0.f;
    if (tt == 2) {
      const int jb = jq << 7;
#pragma unroll 8
      for (int jj = 0; jj < 128; jj += 4) {
        const int j = jb + jj;
        const float4 l4 = *(const float4*)&lv[j];
        const float4 r0 = *(const float4*)&rvd[j + k4];
        const float4 r1 = *(const float4*)&rvd[j + k4 + 4];
        a0 += l4.x * r0.x + l4.y * r0.y + l4.z * r0.z + l4.w * r0.w;
        a1 += l4.x * r0.y + l4.y * r0.z + l4.z * r0.w + l4.w * r1.x;
        a2 += l4.x * r0.z + l4.y * r0.w + l4.z * r1.x + l4.w * r1.y;
        a3 += l4.x * r0.w + l4.y * r1.x + l4.z * r1.y + l4.w * r1.z;
      }
    }
    cpart[jq][k4 + 0] = a0; cpart[jq][k4 + 1] = a1;
    cpart[jq][k4 + 2] = a2; cpart[jq][k4 + 3] = a3;
    __syncthreads();
    const float ck = cpart[0][tid] + cpart[1][tid] + cpart[2][tid] + cpart[3][tid];
    float ss = ck * ck;
#pragma unroll
    for (int off = 32; off; off >>= 1) ss += __shfl_down(ss, off);
    if (lane == 0) red[wid] = ss;
    __syncthreads();
    if (tid == 0) {
      float tot = 0.f;
#pragma unroll
      for (int w = 0; w < 8; ++w) tot += red[w];
      red[8] = 1.f / fmaxf(sqrtf(tot), 1e-12f);
    }
    __syncthreads();
    if (tt == 2) {
      vb[(size_t)p * NH + tid] = ck * red[8];
    } else if (tt == 1) {
      vb[(size_t)p * NH + tid] = lv[tid];
    }
    __syncthreads();
  }
}

// ---------------- K6: output GEMMs (word / phrase) ------------------------
template <int MODE>
__global__ __launch_bounds__(256) void k_out(
    const float* __restrict__ vec, const float* __restrict__ W,
    const float* __restrict__ bias, float* __restrict__ out) {
  constexpr int NOUT = MODE ? NPV : NWV;
  __shared__ float As[16][68], Bs[16][68];
  const int tid = threadIdx.x;
  const int n0 = blockIdx.x * 64, m0 = blockIdx.y * 64;
  const int lr = tid >> 2, lc4 = (tid & 3) << 2;
  const int tx = tid & 15, ty = tid >> 4;
  const int m = m0 + lr;
  int vr;
  if (MODE == 0) {
    vr = (m >> 7) * NTOT + (m & 127);
  } else {
    const int bb = m / 127;
    vr = bb * NTOT + NS + (m - bb * 127);
  }
  const float* arow = vec + (size_t)vr * NH;
  const int n = n0 + lr;
  const float* brow = W + (size_t)n * NH;
  const bool bok = (n < NOUT);
  float acc[4][4] = {};
  for (int k0 = 0; k0 < NH; k0 += 16) {
    const float4 a4 = *(const float4*)(arow + k0 + lc4);
    As[lc4 + 0][lr] = a4.x; As[lc4 + 1][lr] = a4.y;
    As[lc4 + 2][lr] = a4.z; As[lc4 + 3][lr] = a4.w;
    float4 b4 = make_float4(0.f, 0.f, 0.f, 0.f);
    if (bok) b4 = *(const float4*)(brow + k0 + lc4);
    Bs[lc4 + 0][lr] = b4.x; Bs[lc4 + 1][lr] = b4.y;
    Bs[lc4 + 2][lr] = b4.z; Bs[lc4 + 3][lr] = b4.w;
    __syncthreads();
#pragma unroll
    for (int kk = 0; kk < 16; ++kk) {
      const float4 av = *(const float4*)&As[kk][ty << 2];
      const float4 bv = *(const float4*)&Bs[kk][tx << 2];
      FMA4x4(acc, av, bv)
    }
    __syncthreads();
  }
#pragma unroll
  for (int i = 0; i < 4; ++i)
#pragma unroll
    for (int j = 0; j < 4; ++j) {
      const int nn = n0 + (tx << 2) + j;
      if (nn < NOUT)
        out[(size_t)(m0 + (ty << 2) + i) * NOUT + nn] = acc[i][j] + bias[nn];
    }
}

// ---------------- K7: labels (int32 -> f32 copy) --------------------------
// NOTE: batch_label is created as jnp.int64 but JAX default x64-disabled
// demotes it to int32 -> harness passes int32. Reading as i64 was round-1 bug.
__global__ __launch_bounds__(256) void k_labels(
    const int* __restrict__ lab, float* __restrict__ outw,
    float* __restrict__ outp) {
  const int i = blockIdx.x * 256 + threadIdx.x;
  if (i < NB * NS) {
    const int b = i >> 7, s = i & 127;
    outw[i] = (float)lab[b * NTOT + s];
  }
  if (i < NB * NSTEPS) {
    const int b = i / 127;
    outp[i] = (float)lab[b * NTOT + NS + (i - b * 127)];
  }
}

extern "C" void kernel_launch(void* const* d_in, const int* in_sizes, int n_in,
                              void* d_out, int out_size, void* d_ws, size_t ws_size,
                              hipStream_t stream) {
  (void)in_sizes; (void)n_in; (void)out_size; (void)ws_size;
  const float* elmo     = (const float*)d_in[0];
  const float* w_ih_f   = (const float*)d_in[1];
  const float* w_hh_f   = (const float*)d_in[2];
  const float* b_f      = (const float*)d_in[3];
  const float* w_ih_b   = (const float*)d_in[4];
  const float* w_hh_b   = (const float*)d_in[5];
  const float* b_b      = (const float*)d_in[6];
  const float* W1       = (const float*)d_in[7];
  const float* W2       = (const float*)d_in[8];
  const float* word_W   = (const float*)d_in[9];
  const float* word_b   = (const float*)d_in[10];
  const float* phrase_W = (const float*)d_in[11];
  const float* phrase_b = (const float*)d_in[12];
  const int* cinfo      = (const int*)d_in[13];
  // d_in[14] = original_pos: identity (arange,arange) by construction
  const int* lab        = (const int*)d_in[15];

  float* ws    = (float*)d_ws;
  float* xp    = ws;
  float* h_all = xp + XP_SZ;
  float* vec   = h_all + H_SZ;
  int* bar     = (int*)(vec + VEC_SZ);

  float* out_word = (float*)d_out;                       // 8192 x 511
  float* out_phr  = out_word + (size_t)8192 * NWV;       // 8128 x 152
  float* out_lw   = out_phr + (size_t)8128 * NPV;        // 8192
  float* out_lp   = out_lw + 8192;                       // 8128

  k_xp<<<dim3(64, 128), 256, 0, stream>>>(elmo, w_ih_f, w_ih_b, b_f, b_b, xp, bar);
  k_lstm<<<dim3(256), 256, 0, stream>>>(w_hh_f, w_hh_b, xp, h_all, bar);
  k_comb<<<dim3(8, 128), 256, 0, stream>>>(h_all, W1, W2, vec);
  k_norm<<<dim3(2048), 256, 0, stream>>>(vec);
  k_compose<<<dim3(64), 512, 0, stream>>>(vec, cinfo);
  k_out<0><<<dim3(8, 128), 256, 0, stream>>>(vec, word_W, word_b, out_word);
  k_out<1><<<dim3(3, 127), 256, 0, stream>>>(vec, phrase_W, phrase_b, out_phr);
  k_labels<<<dim3(32), 256, 0, stream>>>(lab, out_lw, out_lp);
}